// Round 1
// baseline (1358.964 us; speedup 1.0000x reference)
//
#include <hip/hip_runtime.h>
#include <math.h>
#include <cstdint>

#define B_ 4
#define C_ 384
#define V_ 8
#define H_ 181
#define W_ 360
#define HW_ (H_*W_)      // 65160
#define NP_ (B_*HW_)     // 260640
#define HP_ (H_+4)       // 185
#define WP_ (W_+4)       // 364

// ------------------------------------------------------------------
// Kernel 1: LayerNorm stats over channel axis (per (b,h,w) position)
// ------------------------------------------------------------------
__global__ __launch_bounds__(256) void k_stats(const float* __restrict__ x,
                                               float* __restrict__ meanv,
                                               float* __restrict__ varv) {
  int p = blockIdx.x * 256 + threadIdx.x;
  if (p >= NP_) return;
  int b = p / HW_, hw = p - b * HW_;
  const float* xp = x + (size_t)b * C_ * HW_ + hw;
  float s = 0.f, s2 = 0.f;
#pragma unroll 8
  for (int c = 0; c < C_; ++c) {
    float v = xp[(size_t)c * HW_];
    s += v;
    s2 = fmaf(v, v, s2);
  }
  float m = s * (1.0f / C_);
  float var = fmaf(-m, m, s2 * (1.0f / C_));
  meanv[p] = m;
  varv[p] = var < 0.f ? 0.f : var;
}

// ------------------------------------------------------------------
// Kernel 2: LN apply + geo-pad depthwise 3x3 + 1x1 (C->16) velocity
//           + 1x1 (C->8) down-projection of the RAW input.
// Tile: 32x8 pixels per 256-thread block, halo staged in LDS.
// ------------------------------------------------------------------
#define TW 32
#define TH 8
#define HALO_W (TW + 2)          // 34
#define HALO_H (TH + 2)          // 10
#define NHALO (HALO_W * HALO_H)  // 340
#define KC 16
#define NTW ((W_ + TW - 1) / TW) // 12
#define NTH ((H_ + TH - 1) / TH) // 23

__global__ __launch_bounds__(256) void k_vel(
    const float* __restrict__ x, const float* __restrict__ meanv,
    const float* __restrict__ varv, const float* __restrict__ scale,
    const float* __restrict__ bias, const float* __restrict__ dwk,
    const float* __restrict__ dwb, const float* __restrict__ pw_w,
    const float* __restrict__ pw_b, const float* __restrict__ down_w,
    const float* __restrict__ down_b, float* __restrict__ vel,
    float* __restrict__ proj) {
  __shared__ float xn[KC][NHALO];
  __shared__ float mh[NHALO];
  __shared__ float rh[NHALO];
  __shared__ int offh[NHALO];

  int tid = threadIdx.x;
  int bw = blockIdx.x % NTW;
  int bh = (blockIdx.x / NTW) % NTH;
  int b  = blockIdx.x / (NTW * NTH);
  int w0 = bw * TW, h0 = bh * TH;

  // Precompute geo-cyclic halo source mapping + stats per halo pixel.
  for (int i = tid; i < NHALO; i += 256) {
    int hy = i / HALO_W, hx = i - hy * HALO_W;
    int hh = h0 - 1 + hy;
    int ww = w0 - 1 + hx;
    int hs, sh = 0;
    if (hh < 0)        { hs = -1 - hh;        sh = 1; }
    else if (hh >= H_) { hs = 2 * H_ - 1 - hh; sh = 1; }
    else               { hs = hh; }
    if (hs < 0) hs = 0;
    if (hs >= H_) hs = H_ - 1;
    int ws = ww + (sh ? 180 : 0);
    ws = ((ws % W_) + W_) % W_;
    int off = hs * W_ + ws;
    offh[i] = off;
    float m = meanv[(size_t)b * HW_ + off];
    float v = varv[(size_t)b * HW_ + off];
    mh[i] = m;
    rh[i] = rsqrtf(v + 1e-5f);
  }
  __syncthreads();

  int tx = tid % TW, ty = tid / TW;
  int hp = h0 + ty, wp = w0 + tx;
  bool active = (hp < H_) && (wp < W_);
  int pc = (ty + 1) * HALO_W + (tx + 1);
  float m_c = mh[pc];
  float sd_c = 1.0f / rh[pc];  // sqrt(var+eps)

  float acc_v[16];
  float acc_p[8];
#pragma unroll
  for (int o = 0; o < 16; ++o) acc_v[o] = 0.f;
#pragma unroll
  for (int j = 0; j < 8; ++j) acc_p[j] = 0.f;

  const float* xb = x + (size_t)b * C_ * HW_;

  for (int c0 = 0; c0 < C_; c0 += KC) {
    __syncthreads();  // previous compute done before overwriting LDS
    for (int i = tid; i < KC * NHALO; i += 256) {
      int cl = i / NHALO, pp = i - cl * NHALO;
      float v = xb[(size_t)(c0 + cl) * HW_ + offh[pp]];
      xn[cl][pp] = (v - mh[pp]) * rh[pp];
    }
    __syncthreads();
    if (active) {
#pragma unroll
      for (int cl = 0; cl < KC; ++cl) {
        int c = c0 + cl;
        const float* kk = dwk + c * 9;
        float a = 0.f, ks = 0.f;
#pragma unroll
        for (int dy = 0; dy < 3; ++dy) {
#pragma unroll
          for (int dx = 0; dx < 3; ++dx) {
            float kv = kk[dy * 3 + dx];
            ks += kv;
            a = fmaf(xn[cl][(ty + dy) * HALO_W + (tx + dx)], kv, a);
          }
        }
        float t = fmaf(scale[c], a, fmaf(bias[c], ks, dwb[c]));
#pragma unroll
        for (int o = 0; o < 16; ++o)
          acc_v[o] = fmaf(t, pw_w[o * C_ + c], acc_v[o]);
        float xc = fmaf(xn[cl][pc], sd_c, m_c);  // raw input value
#pragma unroll
        for (int j = 0; j < 8; ++j)
          acc_p[j] = fmaf(xc, down_w[j * C_ + c], acc_p[j]);
      }
    }
  }

  if (active) {
    int hw = hp * W_ + wp;
#pragma unroll
    for (int o = 0; o < 16; ++o)
      vel[((size_t)b * 16 + o) * HW_ + hw] = acc_v[o] + pw_b[o];
#pragma unroll
    for (int j = 0; j < 8; ++j)
      proj[((size_t)b * 8 + j) * HW_ + hw] = acc_p[j] + down_b[j];
  }
}

// ------------------------------------------------------------------
// Kernel 3: departure points + bicubic geo-sample + 1x1 up (8->384)
// ------------------------------------------------------------------
__device__ __forceinline__ void cubw(float t, float w[4]) {
  const float A = -0.75f;
  float t1 = t + 1.0f;
  w[0] = ((A * t1 - 5.0f * A) * t1 + 8.0f * A) * t1 - 4.0f * A;
  w[1] = ((A + 2.0f) * t - (A + 3.0f)) * t * t + 1.0f;
  float s = 1.0f - t;
  w[2] = ((A + 2.0f) * s - (A + 3.0f)) * s * s + 1.0f;
  float t2 = 2.0f - t;
  w[3] = ((A * t2 - 5.0f * A) * t2 + 8.0f * A) * t2 - 4.0f * A;
}

__global__ __launch_bounds__(256) void k_samp(
    const float* __restrict__ vel, const float* __restrict__ proj,
    const float* __restrict__ latg, const float* __restrict__ lonG,
    const float* __restrict__ dtp, const float* __restrict__ up_w,
    const float* __restrict__ up_b, float* __restrict__ out) {
  int p = blockIdx.x * 256 + threadIdx.x;
  if (p >= NP_) return;
  int b = p / HW_, hw = p - b * HW_;

  const float TWO_PI = 6.28318530717958647692f;
  const float X_SCALE = 57.295779513082320877f;  // (W-1)/max_lon = W/(2*pi)
  const float MIN_LAT = -1.57079632679489661923f;
  const float Y_SCALE = 57.295779513082320877f;  // (H-1)/pi

  float dt = dtp[0];
  float lat_p = latg[p];
  float lon_p = lonG[p];
  float sin_p, cos_p;
  sincosf(lat_p, &sin_p, &cos_p);

  float samp[V_];
  const float* projb = proj + (size_t)b * V_ * HW_;

  for (int vch = 0; vch < V_; ++vch) {
    float u  = vel[((size_t)b * 16 + vch) * HW_ + hw];
    float vv = vel[((size_t)b * 16 + 8 + vch) * HW_ + hw];
    float lon_pr = -u * dt;
    float lat_pr = -vv * dt;
    float s_lp, c_lp, s_op, c_op;
    sincosf(lat_pr, &s_lp, &c_lp);
    sincosf(lon_pr, &s_op, &c_op);
    float sin_lat = s_lp * cos_p + c_lp * c_op * sin_p;
    sin_lat = fminf(fmaxf(sin_lat, -1.0f + 1e-7f), 1.0f - 1e-7f);
    float lat_dep = asinf(sin_lat);
    float num = c_lp * s_op;
    float den = c_lp * c_op * cos_p - s_lp * sin_p;
    float lon_dep = fmodf(lon_p + atan2f(num, den) + TWO_PI, TWO_PI);

    float xf = fmaf(lon_dep, X_SCALE, 2.0f);            // pix_x + PAD
    float yf = fmaf(lat_dep - MIN_LAT, Y_SCALE, 2.0f);  // pix_y + PAD

    float x0f = floorf(xf), txf = xf - x0f;
    float y0f = floorf(yf), tyf = yf - y0f;
    int ix0 = (int)x0f, iy0 = (int)y0f;
    float wx[4], wy[4];
    cubw(txf, wx);
    cubw(tyf, wy);

    const float* pv = projb + (size_t)vch * HW_;
    float acc = 0.f;
#pragma unroll
    for (int i = 0; i < 4; ++i) {
      int yi = iy0 - 1 + i;
      yi = yi < 0 ? 0 : (yi > HP_ - 1 ? HP_ - 1 : yi);
      int hh = yi - 2;
      int hs, sh = 0;
      if (hh < 0)        { hs = -1 - hh;         sh = 1; }
      else if (hh >= H_) { hs = 2 * H_ - 1 - hh; sh = 1; }
      else               { hs = hh; }
      const float* row = pv + hs * W_;
      int shoff = sh ? 180 : 0;
      float r = 0.f;
#pragma unroll
      for (int j = 0; j < 4; ++j) {
        int xi = ix0 - 1 + j;
        xi = xi < 0 ? 0 : (xi > WP_ - 1 ? WP_ - 1 : xi);
        int ww = xi - 2 + shoff;
        ww = ((ww % W_) + W_) % W_;
        r = fmaf(row[ww], wx[j], r);
      }
      acc = fmaf(r, wy[i], acc);
    }
    samp[vch] = acc;
  }

  // up conv: out[b,c,h,w] = sum_v samp[v] * up_w[c,v] + up_b[c]
  float* ob = out + (size_t)b * C_ * HW_ + hw;
  for (int c = 0; c < C_; ++c) {
    float o = up_b[c];
#pragma unroll
    for (int v = 0; v < V_; ++v) o = fmaf(samp[v], up_w[c * V_ + v], o);
    ob[(size_t)c * HW_] = o;
  }
}

// ------------------------------------------------------------------
extern "C" void kernel_launch(void* const* d_in, const int* in_sizes, int n_in,
                              void* d_out, int out_size, void* d_ws,
                              size_t ws_size, hipStream_t stream) {
  const float* hidden = (const float*)d_in[0];
  const float* latg   = (const float*)d_in[1];
  const float* lonG   = (const float*)d_in[2];
  const float* dtp    = (const float*)d_in[3];
  const float* nsc    = (const float*)d_in[4];
  const float* nbi    = (const float*)d_in[5];
  const float* dwk    = (const float*)d_in[6];
  const float* dwb    = (const float*)d_in[7];
  const float* pw_w   = (const float*)d_in[8];
  const float* pw_b   = (const float*)d_in[9];
  const float* down_w = (const float*)d_in[10];
  const float* down_b = (const float*)d_in[11];
  const float* up_w   = (const float*)d_in[12];
  const float* up_b   = (const float*)d_in[13];
  float* out = (float*)d_out;

  float* ws   = (float*)d_ws;
  float* meanv = ws;                 // NP_
  float* varv  = ws + NP_;           // NP_
  float* vel   = ws + 2 * NP_;       // 16*NP_
  float* proj  = ws + 18 * (size_t)NP_;  // 8*NP_

  int nblk = (NP_ + 255) / 256;
  hipLaunchKernelGGL(k_stats, dim3(nblk), dim3(256), 0, stream, hidden, meanv,
                     varv);
  hipLaunchKernelGGL(k_vel, dim3(B_ * NTH * NTW), dim3(256), 0, stream, hidden,
                     meanv, varv, nsc, nbi, dwk, dwb, pw_w, pw_b, down_w,
                     down_b, vel, proj);
  hipLaunchKernelGGL(k_samp, dim3(nblk), dim3(256), 0, stream, vel, proj, latg,
                     lonG, dtp, up_w, up_b, out);
}

// Round 2
// 832.603 us; speedup vs baseline: 1.6322x; 1.6322x over previous
//
#include <hip/hip_runtime.h>
#include <math.h>
#include <cstdint>

#define B_ 4
#define C_ 384
#define V_ 8
#define H_ 181
#define W_ 360
#define HW_ (H_*W_)      // 65160
#define NP_ (B_*HW_)     // 260640
#define HP_ (H_+4)       // 185
#define WP_ (W_+4)       // 364

// ------------------------------------------------------------------
// Kernel 1: LayerNorm stats: mean + rstd per (b,h,w)
// ------------------------------------------------------------------
__global__ __launch_bounds__(256) void k_stats(const float* __restrict__ x,
                                               float* __restrict__ meanv,
                                               float* __restrict__ rstdv) {
  int p = blockIdx.x * 256 + threadIdx.x;
  if (p >= NP_) return;
  int b = p / HW_, hw = p - b * HW_;
  const float* xp = x + (size_t)b * C_ * HW_ + hw;
  float s = 0.f, s2 = 0.f;
#pragma unroll 8
  for (int c = 0; c < C_; ++c) {
    float v = xp[(size_t)c * HW_];
    s += v;
    s2 = fmaf(v, v, s2);
  }
  float m = s * (1.0f / C_);
  float var = fmaf(-m, m, s2 * (1.0f / C_));
  var = var < 0.f ? 0.f : var;
  meanv[p] = m;
  rstdv[p] = rsqrtf(var + 1e-5f);
}

// ------------------------------------------------------------------
// Kernel 2: LN apply + geo-pad depthwise 3x3 + 1x1 (C->16) velocity
//           + 1x1 (C->8) down-proj, channel-split x4, atomic accum.
// Tile 32x16 pixels, 256 threads (2 vertical px/thread), halo in LDS.
// ------------------------------------------------------------------
#define TW 32
#define TH 16
#define HALO_W (TW + 2)          // 34
#define HALO_H (TH + 2)          // 18
#define NHALO (HALO_W * HALO_H)  // 612
#define KC 8
#define CSPLIT 4
#define CPB (C_ / CSPLIT)        // 96
#define NCHUNK (CPB / KC)        // 12
#define NTW ((W_ + TW - 1) / TW) // 12
#define NTH ((H_ + TH - 1) / TH) // 12

__global__ __launch_bounds__(256, 4) void k_vel(
    const float* __restrict__ x, const float* __restrict__ meanv,
    const float* __restrict__ rstdv, const float* __restrict__ scale,
    const float* __restrict__ dwk, const float* __restrict__ pw_w,
    const float* __restrict__ down_w, float* __restrict__ vel,
    float* __restrict__ proj) {
  __shared__ float xn[KC][NHALO];
  __shared__ float mh[NHALO];
  __shared__ float rh[NHALO];
  __shared__ int offh[NHALO];

  int tid = threadIdx.x;
  int bx = blockIdx.x;
  int bw = bx % NTW; bx /= NTW;
  int bh = bx % NTH; bx /= NTH;
  int b  = bx % B_;
  int sl = bx / B_;
  int w0 = bw * TW, h0 = bh * TH;
  int cbase = sl * CPB;

  // halo source mapping + per-pixel stats
  for (int i = tid; i < NHALO; i += 256) {
    int hy = i / HALO_W, hx = i - hy * HALO_W;
    int hh = h0 - 1 + hy;
    int ww = w0 - 1 + hx;
    int hs, sh = 0;
    if (hh < 0)        { hs = -1 - hh;         sh = 180; }
    else if (hh >= H_) { hs = 2 * H_ - 1 - hh; sh = 180; }
    else               { hs = hh; }
    int ws = ww + sh;
    ws = ((ws % W_) + W_) % W_;
    int off = hs * W_ + ws;
    offh[i] = off;
    mh[i] = meanv[(size_t)b * HW_ + off];
    rh[i] = rstdv[(size_t)b * HW_ + off];
  }
  __syncthreads();

  int tx = tid & 31, ty = tid >> 5;  // ty 0..7
  int r0 = 2 * ty;                   // halo row of top tap for pixel 0
  int hp0 = h0 + r0, hp1 = hp0 + 1;
  int wp = w0 + tx;
  bool act0 = (hp0 < H_) && (wp < W_);
  bool act1 = (hp1 < H_) && (wp < W_);
  int pc0 = (r0 + 1) * HALO_W + tx + 1;
  int pc1 = pc0 + HALO_W;
  float m0 = mh[pc0], m1 = mh[pc1];
  float sd0 = 1.0f / rh[pc0], sd1 = 1.0f / rh[pc1];

  float av0[16], av1[16], ap0[8], ap1[8];
#pragma unroll
  for (int o = 0; o < 16; ++o) { av0[o] = 0.f; av1[o] = 0.f; }
#pragma unroll
  for (int j = 0; j < 8; ++j) { ap0[j] = 0.f; ap1[j] = 0.f; }

  const float* xb = x + (size_t)b * C_ * HW_;

  for (int chunk = 0; chunk < NCHUNK; ++chunk) {
    int c0 = cbase + chunk * KC;
    __syncthreads();
#pragma unroll
    for (int cl = 0; cl < KC; ++cl) {
      const float* xc = xb + (size_t)(c0 + cl) * HW_;
      for (int i = tid; i < NHALO; i += 256)
        xn[cl][i] = (xc[offh[i]] - mh[i]) * rh[i];
    }
    __syncthreads();
#pragma unroll 2
    for (int cl = 0; cl < KC; ++cl) {
      int c = c0 + cl;  // wave-uniform -> weight reads become s_load
      float xr[4][3];
#pragma unroll
      for (int dy = 0; dy < 4; ++dy)
#pragma unroll
        for (int dx = 0; dx < 3; ++dx)
          xr[dy][dx] = xn[cl][(r0 + dy) * HALO_W + tx + dx];
      const float* kk = dwk + c * 9;
      float a0 = 0.f, a1 = 0.f;
#pragma unroll
      for (int dy = 0; dy < 3; ++dy)
#pragma unroll
        for (int dx = 0; dx < 3; ++dx) {
          float kv = kk[dy * 3 + dx];
          a0 = fmaf(xr[dy][dx], kv, a0);
          a1 = fmaf(xr[dy + 1][dx], kv, a1);
        }
      float sc = scale[c];
      a0 *= sc;
      a1 *= sc;
      float xc0 = fmaf(xr[1][1], sd0, m0);  // raw center value px0
      float xc1 = fmaf(xr[2][1], sd1, m1);  // raw center value px1
#pragma unroll
      for (int o = 0; o < 16; ++o) {
        float w = pw_w[o * C_ + c];
        av0[o] = fmaf(a0, w, av0[o]);
        av1[o] = fmaf(a1, w, av1[o]);
      }
#pragma unroll
      for (int j = 0; j < 8; ++j) {
        float w = down_w[j * C_ + c];
        ap0[j] = fmaf(xc0, w, ap0[j]);
        ap1[j] = fmaf(xc1, w, ap1[j]);
      }
    }
  }

  int hw0 = hp0 * W_ + wp;
  int hw1 = hw0 + W_;
  if (act0) {
#pragma unroll
    for (int o = 0; o < 16; ++o)
      atomicAdd(&vel[((size_t)b * 16 + o) * HW_ + hw0], av0[o]);
#pragma unroll
    for (int j = 0; j < 8; ++j)
      atomicAdd(&proj[((size_t)b * 8 + j) * HW_ + hw0], ap0[j]);
  }
  if (act1) {
#pragma unroll
    for (int o = 0; o < 16; ++o)
      atomicAdd(&vel[((size_t)b * 16 + o) * HW_ + hw1], av1[o]);
#pragma unroll
    for (int j = 0; j < 8; ++j)
      atomicAdd(&proj[((size_t)b * 8 + j) * HW_ + hw1], ap1[j]);
  }
}

// ------------------------------------------------------------------
// Kernel 2.5: fold biases: vbias[o<16] = pw_b[o] + sum_c pw_w[o,c]*
//             (bias[c]*ksum[c] + dwb[c]);  vbias[16+j] = down_b[j]
// ------------------------------------------------------------------
__global__ void k_prep(const float* __restrict__ bias,
                       const float* __restrict__ dwk,
                       const float* __restrict__ dwb,
                       const float* __restrict__ pw_w,
                       const float* __restrict__ pw_b,
                       const float* __restrict__ down_b,
                       float* __restrict__ vbias) {
  __shared__ float sb[C_];
  int t = threadIdx.x;
  if (t < C_) {
    float ks = 0.f;
#pragma unroll
    for (int k = 0; k < 9; ++k) ks += dwk[t * 9 + k];
    sb[t] = bias[t] * ks + dwb[t];
  }
  __syncthreads();
  if (t < 16) {
    float acc = pw_b[t];
    for (int c = 0; c < C_; ++c) acc = fmaf(pw_w[t * C_ + c], sb[c], acc);
    vbias[t] = acc;
  } else if (t < 24) {
    vbias[t] = down_b[t - 16];
  }
}

// ------------------------------------------------------------------
// Kernel 3: departure points + bicubic geo-sample + 1x1 up (8->384)
// ------------------------------------------------------------------
__device__ __forceinline__ void cubw(float t, float w[4]) {
  const float A = -0.75f;
  float t1 = t + 1.0f;
  w[0] = ((A * t1 - 5.0f * A) * t1 + 8.0f * A) * t1 - 4.0f * A;
  w[1] = ((A + 2.0f) * t - (A + 3.0f)) * t * t + 1.0f;
  float s = 1.0f - t;
  w[2] = ((A + 2.0f) * s - (A + 3.0f)) * s * s + 1.0f;
  float t2 = 2.0f - t;
  w[3] = ((A * t2 - 5.0f * A) * t2 + 8.0f * A) * t2 - 4.0f * A;
}

__global__ __launch_bounds__(256) void k_samp(
    const float* __restrict__ vel, const float* __restrict__ proj,
    const float* __restrict__ latg, const float* __restrict__ lonG,
    const float* __restrict__ dtp, const float* __restrict__ up_w,
    const float* __restrict__ up_b, const float* __restrict__ vbias,
    float* __restrict__ out) {
  int p = blockIdx.x * 256 + threadIdx.x;
  if (p >= NP_) return;
  int b = p / HW_, hw = p - b * HW_;

  const float TWO_PI = 6.28318530717958647692f;
  const float X_SCALE = 57.295779513082320877f;  // W/(2*pi)
  const float MIN_LAT = -1.57079632679489661923f;
  const float Y_SCALE = 57.295779513082320877f;  // (H-1)/pi

  float dt = dtp[0];
  float lat_p = latg[p];
  float lon_p = lonG[p];
  float sin_p, cos_p;
  sincosf(lat_p, &sin_p, &cos_p);

  float samp[V_];
  const float* projb = proj + (size_t)b * V_ * HW_;

  for (int vch = 0; vch < V_; ++vch) {
    float u  = vel[((size_t)b * 16 + vch) * HW_ + hw] + vbias[vch];
    float vv = vel[((size_t)b * 16 + 8 + vch) * HW_ + hw] + vbias[8 + vch];
    float lon_pr = -u * dt;
    float lat_pr = -vv * dt;
    float s_lp, c_lp, s_op, c_op;
    sincosf(lat_pr, &s_lp, &c_lp);
    sincosf(lon_pr, &s_op, &c_op);
    float sin_lat = s_lp * cos_p + c_lp * c_op * sin_p;
    sin_lat = fminf(fmaxf(sin_lat, -1.0f + 1e-7f), 1.0f - 1e-7f);
    float lat_dep = asinf(sin_lat);
    float num = c_lp * s_op;
    float den = c_lp * c_op * cos_p - s_lp * sin_p;
    float lon_dep = fmodf(lon_p + atan2f(num, den) + TWO_PI, TWO_PI);

    float xf = fmaf(lon_dep, X_SCALE, 2.0f);            // pix_x + PAD
    float yf = fmaf(lat_dep - MIN_LAT, Y_SCALE, 2.0f);  // pix_y + PAD

    float x0f = floorf(xf), txf = xf - x0f;
    float y0f = floorf(yf), tyf = yf - y0f;
    int ix0 = (int)x0f, iy0 = (int)y0f;
    float wx[4], wy[4];
    cubw(txf, wx);
    cubw(tyf, wy);

    const float* pv = projb + (size_t)vch * HW_;
    float acc = 0.f;
#pragma unroll
    for (int i = 0; i < 4; ++i) {
      int yi = iy0 - 1 + i;
      yi = yi < 0 ? 0 : (yi > HP_ - 1 ? HP_ - 1 : yi);
      int hh = yi - 2;
      int hs, sh = 0;
      if (hh < 0)        { hs = -1 - hh;         sh = 1; }
      else if (hh >= H_) { hs = 2 * H_ - 1 - hh; sh = 1; }
      else               { hs = hh; }
      const float* row = pv + hs * W_;
      int shoff = sh ? 180 : 0;
      float r = 0.f;
#pragma unroll
      for (int j = 0; j < 4; ++j) {
        int xi = ix0 - 1 + j;
        xi = xi < 0 ? 0 : (xi > WP_ - 1 ? WP_ - 1 : xi);
        int ww = xi - 2 + shoff;
        ww = ((ww % W_) + W_) % W_;
        r = fmaf(row[ww], wx[j], r);
      }
      acc = fmaf(r, wy[i], acc);
    }
    samp[vch] = acc + vbias[16 + vch];  // down_b post-sample (weights sum to 1)
  }

  float* ob = out + (size_t)b * C_ * HW_ + hw;
  for (int c = 0; c < C_; ++c) {
    float o = up_b[c];
#pragma unroll
    for (int v = 0; v < V_; ++v) o = fmaf(samp[v], up_w[c * V_ + v], o);
    ob[(size_t)c * HW_] = o;
  }
}

// ------------------------------------------------------------------
extern "C" void kernel_launch(void* const* d_in, const int* in_sizes, int n_in,
                              void* d_out, int out_size, void* d_ws,
                              size_t ws_size, hipStream_t stream) {
  const float* hidden = (const float*)d_in[0];
  const float* latg   = (const float*)d_in[1];
  const float* lonG   = (const float*)d_in[2];
  const float* dtp    = (const float*)d_in[3];
  const float* nsc    = (const float*)d_in[4];
  const float* nbi    = (const float*)d_in[5];
  const float* dwk    = (const float*)d_in[6];
  const float* dwb    = (const float*)d_in[7];
  const float* pw_w   = (const float*)d_in[8];
  const float* pw_b   = (const float*)d_in[9];
  const float* down_w = (const float*)d_in[10];
  const float* down_b = (const float*)d_in[11];
  const float* up_w   = (const float*)d_in[12];
  const float* up_b   = (const float*)d_in[13];
  float* out = (float*)d_out;

  float* ws    = (float*)d_ws;
  float* meanv = ws;                       // NP_
  float* rstdv = ws + NP_;                 // NP_
  float* vel   = ws + 2 * (size_t)NP_;     // 16*NP_
  float* proj  = ws + 18 * (size_t)NP_;    // 8*NP_
  float* vbias = rstdv;  // first 24 floats of rstdv, reused AFTER k_vel

  int nblk = (NP_ + 255) / 256;
  hipLaunchKernelGGL(k_stats, dim3(nblk), dim3(256), 0, stream, hidden, meanv,
                     rstdv);
  // zero the atomic accumulation buffers (vel+proj contiguous: 24*NP_)
  hipMemsetAsync(vel, 0, (size_t)24 * NP_ * sizeof(float), stream);
  hipLaunchKernelGGL(k_vel, dim3(NTW * NTH * B_ * CSPLIT), dim3(256), 0,
                     stream, hidden, meanv, rstdv, nsc, dwk, pw_w, down_w, vel,
                     proj);
  hipLaunchKernelGGL(k_prep, dim3(1), dim3(C_), 0, stream, nbi, dwk, dwb, pw_w,
                     pw_b, down_b, vbias);
  hipLaunchKernelGGL(k_samp, dim3(nblk), dim3(256), 0, stream, vel, proj, latg,
                     lonG, dtp, up_w, up_b, vbias, out);
}

// Round 3
// 646.668 us; speedup vs baseline: 2.1015x; 1.2875x over previous
//
#include <hip/hip_runtime.h>
#include <math.h>
#include <cstdint>

#define B_ 4
#define C_ 384
#define V_ 8
#define H_ 181
#define W_ 360
#define HW_ (H_*W_)      // 65160
#define NP_ (B_*HW_)     // 260640
#define HP_ (H_+4)       // 185
#define WP_ (W_+4)       // 364

// ------------------------------------------------------------------
// k_prep: vbias[o] = pw_b[o] + sum_c pw_w[o,c]*(bias[c]*ksum[c]+dwb[c])
// ------------------------------------------------------------------
__global__ void k_prep(const float* __restrict__ bias,
                       const float* __restrict__ dwk,
                       const float* __restrict__ dwb,
                       const float* __restrict__ pw_w,
                       const float* __restrict__ pw_b,
                       float* __restrict__ vbias) {
  __shared__ float sb[C_];
  int t = threadIdx.x;
  if (t < C_) {
    float ks = 0.f;
#pragma unroll
    for (int k = 0; k < 9; ++k) ks += dwk[t * 9 + k];
    sb[t] = bias[t] * ks + dwb[t];
  }
  __syncthreads();
  if (t < 16) {
    float acc = pw_b[t];
    for (int c = 0; c < C_; ++c) acc = fmaf(pw_w[t * C_ + c], sb[c], acc);
    vbias[t] = acc;
  }
}

// ------------------------------------------------------------------
// k_stats: LN mean/rstd per pixel + fused down-proj (raw x, 1x1 C->8)
// ------------------------------------------------------------------
__global__ __launch_bounds__(256) void k_stats(
    const float* __restrict__ x, const float* __restrict__ down_w,
    const float* __restrict__ down_b, float* __restrict__ meanv,
    float* __restrict__ rstdv, float* __restrict__ proj) {
  int p = blockIdx.x * 256 + threadIdx.x;
  if (p >= NP_) return;
  int b = p / HW_, hw = p - b * HW_;
  const float* xp = x + (size_t)b * C_ * HW_ + hw;

  float sA = 0.f, sB = 0.f, s2A = 0.f, s2B = 0.f;
  float apA[8], apB[8];
#pragma unroll
  for (int j = 0; j < 8; ++j) { apA[j] = 0.f; apB[j] = 0.f; }

#pragma unroll 4
  for (int c = 0; c < C_ / 2; ++c) {
    float v0 = xp[(size_t)c * HW_];
    float v1 = xp[(size_t)(c + C_ / 2) * HW_];
    sA += v0;
    sB += v1;
    s2A = fmaf(v0, v0, s2A);
    s2B = fmaf(v1, v1, s2B);
#pragma unroll
    for (int j = 0; j < 8; ++j) {
      apA[j] = fmaf(v0, down_w[j * C_ + c], apA[j]);
      apB[j] = fmaf(v1, down_w[j * C_ + c + C_ / 2], apB[j]);
    }
  }
  float m = (sA + sB) * (1.0f / C_);
  float var = fmaf(-m, m, (s2A + s2B) * (1.0f / C_));
  var = var < 0.f ? 0.f : var;
  meanv[p] = m;
  rstdv[p] = rsqrtf(var + 1e-5f);
#pragma unroll
  for (int j = 0; j < 8; ++j)
    proj[((size_t)b * 8 + j) * HW_ + hw] = apA[j] + apB[j] + down_b[j];
}

// ------------------------------------------------------------------
// k_vel: LN apply + geo-pad depthwise 3x3 + 1x1 (C->16) velocity.
// Tile 32x8 px, 1 px/thread, register-prefetch software pipeline.
// ------------------------------------------------------------------
#define TW 32
#define TH 8
#define HALO_W (TW + 2)          // 34
#define HALO_H (TH + 2)          // 10
#define NHALO (HALO_W * HALO_H)  // 340
#define KC 16
#define NCHUNK (C_ / KC)         // 24
#define NTW ((W_ + TW - 1) / TW) // 12
#define NTH ((H_ + TH - 1) / TH) // 23

__device__ __forceinline__ int geo_off(int h0, int w0, int i) {
  int hy = i / HALO_W, hx = i - hy * HALO_W;
  int hh = h0 - 1 + hy;
  int ww = w0 - 1 + hx;
  int hs, sh = 0;
  if (hh < 0)        { hs = -1 - hh;         sh = 180; }
  else if (hh >= H_) { hs = 2 * H_ - 1 - hh; sh = 180; }
  else               { hs = hh; }
  int ws2 = ww + sh;
  ws2 = ((ws2 % W_) + W_) % W_;
  return hs * W_ + ws2;
}

__global__ __launch_bounds__(256) void k_vel(
    const float* __restrict__ x, const float* __restrict__ meanv,
    const float* __restrict__ rstdv, const float* __restrict__ scale,
    const float* __restrict__ dwk, const float* __restrict__ pw_w,
    float* __restrict__ vel) {
  __shared__ float xn[KC][NHALO];

  int tid = threadIdx.x;
  int bx = blockIdx.x;
  int bw = bx % NTW; bx /= NTW;
  int bh = bx % NTH;
  int b  = bx / NTH;
  int w0 = bw * TW, h0 = bh * TH;

  // halo cells owned by this thread (geo offsets + stats in registers)
  int i0 = tid, i1 = tid + 256;
  bool has1 = (i1 < NHALO);
  int o0 = geo_off(h0, w0, i0);
  int o1 = has1 ? geo_off(h0, w0, i1) : o0;

  size_t bHW = (size_t)b * HW_;
  float m0v = meanv[bHW + o0], r0v = rstdv[bHW + o0];
  float m1v = 0.f, r1v = 0.f;
  if (has1) { m1v = meanv[bHW + o1]; r1v = rstdv[bHW + o1]; }

  const float* xb0 = x + (size_t)b * C_ * HW_ + o0;
  const float* xb1 = x + (size_t)b * C_ * HW_ + o1;

  float pf0[KC], pf1[KC];
#pragma unroll
  for (int cl = 0; cl < KC; ++cl) pf0[cl] = xb0[(size_t)cl * HW_];
  if (has1) {
#pragma unroll
    for (int cl = 0; cl < KC; ++cl) pf1[cl] = xb1[(size_t)cl * HW_];
  }

  int tx = tid & 31, ty = tid >> 5;
  float acc[16];
#pragma unroll
  for (int o = 0; o < 16; ++o) acc[o] = 0.f;

  for (int chunk = 0; chunk < NCHUNK; ++chunk) {
    // stage (normalized) into LDS from prefetch registers
#pragma unroll
    for (int cl = 0; cl < KC; ++cl) xn[cl][i0] = (pf0[cl] - m0v) * r0v;
    if (has1) {
#pragma unroll
      for (int cl = 0; cl < KC; ++cl) xn[cl][i1] = (pf1[cl] - m1v) * r1v;
    }
    __syncthreads();

    // issue next chunk's loads; consumed at next stage phase
    if (chunk + 1 < NCHUNK) {
      const float* xc0 = xb0 + (size_t)(chunk + 1) * KC * HW_;
#pragma unroll
      for (int cl = 0; cl < KC; ++cl) pf0[cl] = xc0[(size_t)cl * HW_];
      if (has1) {
        const float* xc1 = xb1 + (size_t)(chunk + 1) * KC * HW_;
#pragma unroll
        for (int cl = 0; cl < KC; ++cl) pf1[cl] = xc1[(size_t)cl * HW_];
      }
    }

    // compute on current chunk
    int cb = chunk * KC;
#pragma unroll
    for (int cl = 0; cl < KC; ++cl) {
      int c = cb + cl;  // wave-uniform -> weights come via s_load
      const float* kk = dwk + c * 9;
      float a = 0.f;
#pragma unroll
      for (int dy = 0; dy < 3; ++dy)
#pragma unroll
        for (int dx = 0; dx < 3; ++dx)
          a = fmaf(xn[cl][(ty + dy) * HALO_W + tx + dx], kk[dy * 3 + dx], a);
      a *= scale[c];
#pragma unroll
      for (int o = 0; o < 16; ++o)
        acc[o] = fmaf(a, pw_w[o * C_ + c], acc[o]);
    }
    __syncthreads();
  }

  int hp = h0 + ty, wp = w0 + tx;
  if (hp < H_ && wp < W_) {
    int hw = hp * W_ + wp;
#pragma unroll
    for (int o = 0; o < 16; ++o)
      vel[((size_t)b * 16 + o) * HW_ + hw] = acc[o];
  }
}

// ------------------------------------------------------------------
// k_samp: departure points + bicubic geo-sample + 1x1 up (8->384)
// ------------------------------------------------------------------
__device__ __forceinline__ void cubw(float t, float w[4]) {
  const float A = -0.75f;
  float t1 = t + 1.0f;
  w[0] = ((A * t1 - 5.0f * A) * t1 + 8.0f * A) * t1 - 4.0f * A;
  w[1] = ((A + 2.0f) * t - (A + 3.0f)) * t * t + 1.0f;
  float s = 1.0f - t;
  w[2] = ((A + 2.0f) * s - (A + 3.0f)) * s * s + 1.0f;
  float t2 = 2.0f - t;
  w[3] = ((A * t2 - 5.0f * A) * t2 + 8.0f * A) * t2 - 4.0f * A;
}

__global__ __launch_bounds__(256) void k_samp(
    const float* __restrict__ vel, const float* __restrict__ proj,
    const float* __restrict__ latg, const float* __restrict__ lonG,
    const float* __restrict__ dtp, const float* __restrict__ up_w,
    const float* __restrict__ up_b, const float* __restrict__ vbias,
    float* __restrict__ out) {
  int p = blockIdx.x * 256 + threadIdx.x;
  if (p >= NP_) return;
  int b = p / HW_, hw = p - b * HW_;

  const float TWO_PI = 6.28318530717958647692f;
  const float X_SCALE = 57.295779513082320877f;  // W/(2*pi)
  const float MIN_LAT = -1.57079632679489661923f;
  const float Y_SCALE = 57.295779513082320877f;  // (H-1)/pi

  float dt = dtp[0];
  float lat_p = latg[p];
  float lon_p = lonG[p];
  float sin_p, cos_p;
  sincosf(lat_p, &sin_p, &cos_p);

  float samp[V_];
  const float* projb = proj + (size_t)b * V_ * HW_;

  for (int vch = 0; vch < V_; ++vch) {
    float u  = vel[((size_t)b * 16 + vch) * HW_ + hw] + vbias[vch];
    float vv = vel[((size_t)b * 16 + 8 + vch) * HW_ + hw] + vbias[8 + vch];
    float lon_pr = -u * dt;
    float lat_pr = -vv * dt;
    float s_lp, c_lp, s_op, c_op;
    sincosf(lat_pr, &s_lp, &c_lp);
    sincosf(lon_pr, &s_op, &c_op);
    float sin_lat = s_lp * cos_p + c_lp * c_op * sin_p;
    sin_lat = fminf(fmaxf(sin_lat, -1.0f + 1e-7f), 1.0f - 1e-7f);
    float lat_dep = asinf(sin_lat);
    float num = c_lp * s_op;
    float den = c_lp * c_op * cos_p - s_lp * sin_p;
    float lon_dep = fmodf(lon_p + atan2f(num, den) + TWO_PI, TWO_PI);

    float xf = fmaf(lon_dep, X_SCALE, 2.0f);            // pix_x + PAD
    float yf = fmaf(lat_dep - MIN_LAT, Y_SCALE, 2.0f);  // pix_y + PAD

    float x0f = floorf(xf), txf = xf - x0f;
    float y0f = floorf(yf), tyf = yf - y0f;
    int ix0 = (int)x0f, iy0 = (int)y0f;
    float wx[4], wy[4];
    cubw(txf, wx);
    cubw(tyf, wy);

    const float* pv = projb + (size_t)vch * HW_;
    float acc = 0.f;
#pragma unroll
    for (int i = 0; i < 4; ++i) {
      int yi = iy0 - 1 + i;
      yi = yi < 0 ? 0 : (yi > HP_ - 1 ? HP_ - 1 : yi);
      int hh = yi - 2;
      int hs, sh = 0;
      if (hh < 0)        { hs = -1 - hh;         sh = 1; }
      else if (hh >= H_) { hs = 2 * H_ - 1 - hh; sh = 1; }
      else               { hs = hh; }
      const float* row = pv + hs * W_;
      int shoff = sh ? 180 : 0;
      float r = 0.f;
#pragma unroll
      for (int j = 0; j < 4; ++j) {
        int xi = ix0 - 1 + j;
        xi = xi < 0 ? 0 : (xi > WP_ - 1 ? WP_ - 1 : xi);
        int ww = xi - 2 + shoff;
        ww = ((ww % W_) + W_) % W_;
        r = fmaf(row[ww], wx[j], r);
      }
      acc = fmaf(r, wy[i], acc);
    }
    samp[vch] = acc;  // proj already includes down_b
  }

  float* ob = out + (size_t)b * C_ * HW_ + hw;
  for (int c = 0; c < C_; ++c) {
    float o = up_b[c];
#pragma unroll
    for (int v = 0; v < V_; ++v) o = fmaf(samp[v], up_w[c * V_ + v], o);
    ob[(size_t)c * HW_] = o;
  }
}

// ------------------------------------------------------------------
extern "C" void kernel_launch(void* const* d_in, const int* in_sizes, int n_in,
                              void* d_out, int out_size, void* d_ws,
                              size_t ws_size, hipStream_t stream) {
  const float* hidden = (const float*)d_in[0];
  const float* latg   = (const float*)d_in[1];
  const float* lonG   = (const float*)d_in[2];
  const float* dtp    = (const float*)d_in[3];
  const float* nsc    = (const float*)d_in[4];
  const float* nbi    = (const float*)d_in[5];
  const float* dwk    = (const float*)d_in[6];
  const float* dwb    = (const float*)d_in[7];
  const float* pw_w   = (const float*)d_in[8];
  const float* pw_b   = (const float*)d_in[9];
  const float* down_w = (const float*)d_in[10];
  const float* down_b = (const float*)d_in[11];
  const float* up_w   = (const float*)d_in[12];
  const float* up_b   = (const float*)d_in[13];
  float* out = (float*)d_out;

  float* ws    = (float*)d_ws;
  float* meanv = ws;                       // NP_
  float* rstdv = ws + NP_;                 // NP_
  float* vel   = ws + 2 * (size_t)NP_;     // 16*NP_
  float* proj  = ws + 18 * (size_t)NP_;    // 8*NP_
  float* vbias = ws + 26 * (size_t)NP_;    // 16 floats

  int nblk = (NP_ + 255) / 256;
  hipLaunchKernelGGL(k_prep, dim3(1), dim3(C_), 0, stream, nbi, dwk, dwb, pw_w,
                     pw_b, vbias);
  hipLaunchKernelGGL(k_stats, dim3(nblk), dim3(256), 0, stream, hidden, down_w,
                     down_b, meanv, rstdv, proj);
  hipLaunchKernelGGL(k_vel, dim3(NTW * NTH * B_), dim3(256), 0, stream, hidden,
                     meanv, rstdv, nsc, dwk, pw_w, vel);
  hipLaunchKernelGGL(k_samp, dim3(nblk), dim3(256), 0, stream, vel, proj, latg,
                     lonG, dtp, up_w, up_b, vbias, out);
}